// Round 1
// baseline (4203.159 us; speedup 1.0000x reference)
//
#include <hip/hip_runtime.h>

// Sizes
constexpr int BB = 8;
constexpr int CC = 256;
constexpr int HH = 128;
constexpr int WW = 128;
constexpr int INTER = 64;
constexpr size_t NPIX = (size_t)HH * WW;           // 16384
constexpr size_t C64SZ = (size_t)BB * INTER * NPIX; // 8,388,608
constexpr size_t QSZ   = (size_t)BB * 8 * NPIX;     // 1,048,576
constexpr size_t STATSZ = (size_t)BB * HH * WW;     // 131,072
constexpr size_t OUTHALF = (size_t)BB * CC * NPIX;  // 33,554,432

// ---------------------------------------------------------------------------
// Conv 3x3 (pad 1) + BN(scale,bias) + ReLU.  Each block: 4 rows x 128 cols of
// output for 32 output channels.  Thread = (w, 2 stacked rows).  Weights are
// uniform -> scalar loads (s_load), input tile staged in LDS per ic.
// ---------------------------------------------------------------------------
template<int CIN>
__global__ __launch_bounds__(256) void conv3x3_bn_relu(
    const float* __restrict__ x, const float* __restrict__ wgt,
    const float* __restrict__ bns, const float* __restrict__ bnb,
    float* __restrict__ out, int Cout)
{
    __shared__ float tile[6][132];
    const int tid = threadIdx.x;
    const int w   = tid & 127;
    const int hs  = tid >> 7;          // 0 or 1
    const int h0  = blockIdx.x * 4;
    const int b   = blockIdx.y;
    const int oc0 = blockIdx.z * 32;

    float acc[32][2];
#pragma unroll
    for (int o = 0; o < 32; ++o) { acc[o][0] = 0.f; acc[o][1] = 0.f; }

    const float* xb = x + (size_t)b * CIN * NPIX;

    for (int ic = 0; ic < CIN; ++ic) {
        const float* xc = xb + (size_t)ic * NPIX;
#pragma unroll
        for (int i = 0; i < 4; ++i) {
            int idx = tid + i * 256;
            if (idx < 780) {
                int r   = idx / 130;
                int col = idx - r * 130;
                int gh  = h0 - 1 + r;
                int gw  = col - 1;
                float vv = 0.f;
                if ((unsigned)gh < 128u && (unsigned)gw < 128u)
                    vv = xc[gh * 128 + gw];
                tile[r][col] = vv;
            }
        }
        __syncthreads();

        float iv[4][3];
#pragma unroll
        for (int r = 0; r < 4; ++r)
#pragma unroll
            for (int cc = 0; cc < 3; ++cc)
                iv[r][cc] = tile[hs * 2 + r][w + cc];

        const float* wp0 = wgt + ((size_t)oc0 * CIN + ic) * 9;
#pragma unroll
        for (int o = 0; o < 32; ++o) {
            const float* wp = wp0 + (size_t)o * CIN * 9;
            float w00 = wp[0], w01 = wp[1], w02 = wp[2];
            float w10 = wp[3], w11 = wp[4], w12 = wp[5];
            float w20 = wp[6], w21 = wp[7], w22 = wp[8];
            acc[o][0] += w00*iv[0][0] + w01*iv[0][1] + w02*iv[0][2]
                       + w10*iv[1][0] + w11*iv[1][1] + w12*iv[1][2]
                       + w20*iv[2][0] + w21*iv[2][1] + w22*iv[2][2];
            acc[o][1] += w00*iv[1][0] + w01*iv[1][1] + w02*iv[1][2]
                       + w10*iv[2][0] + w11*iv[2][1] + w12*iv[2][2]
                       + w20*iv[3][0] + w21*iv[3][1] + w22*iv[3][2];
        }
        __syncthreads();
    }

    const int h = h0 + hs * 2;
#pragma unroll
    for (int o = 0; o < 32; ++o) {
        float s  = bns[oc0 + o];
        float bb2 = bnb[oc0 + o];
        float y0 = fmaxf(acc[o][0] * s + bb2, 0.f);
        float y1 = fmaxf(acc[o][1] * s + bb2, 0.f);
        size_t base = (((size_t)b * Cout + oc0 + o) * 128 + h) * 128 + w;
        out[base]        = y0;
        out[base + 128]  = y1;
    }
}

// ---------------------------------------------------------------------------
// QK projection: q = q_w @ xq + q_b (8 ch), k = k_w @ xe + k_b (8 ch)
// ---------------------------------------------------------------------------
__global__ __launch_bounds__(256) void qk_kernel(
    const float* __restrict__ xq, const float* __restrict__ xe,
    const float* __restrict__ qw, const float* __restrict__ qb,
    const float* __restrict__ kw, const float* __restrict__ kb,
    float* __restrict__ q, float* __restrict__ k)
{
    size_t p = (size_t)blockIdx.x * 256 + threadIdx.x;   // 0..131071
    int b = (int)(p >> 14);
    int pix = (int)(p & 16383);
    const float* xqb = xq + (size_t)b * 64 * NPIX + pix;
    const float* xeb = xe + (size_t)b * 64 * NPIX + pix;
    float qa[8], ka[8];
#pragma unroll
    for (int o = 0; o < 8; ++o) { qa[o] = qb[o]; ka[o] = kb[o]; }
    for (int c = 0; c < 64; ++c) {
        float xv = xqb[(size_t)c * NPIX];
        float ev = xeb[(size_t)c * NPIX];
#pragma unroll
        for (int o = 0; o < 8; ++o) {
            qa[o] += qw[o * 64 + c] * xv;
            ka[o] += kw[o * 64 + c] * ev;
        }
    }
#pragma unroll
    for (int o = 0; o < 8; ++o) {
        q[((size_t)b * 8 + o) * NPIX + pix] = qa[o];
        k[((size_t)b * 8 + o) * NPIX + pix] = ka[o];
    }
}

// ---------------------------------------------------------------------------
// V projection: v = v_w @ xe + v_b (64 ch), 32 oc per z-slice
// ---------------------------------------------------------------------------
__global__ __launch_bounds__(256) void v_kernel(
    const float* __restrict__ xe,
    const float* __restrict__ vw, const float* __restrict__ vb,
    float* __restrict__ v)
{
    size_t p = (size_t)blockIdx.x * 256 + threadIdx.x;
    int b = (int)(p >> 14);
    int pix = (int)(p & 16383);
    int oc0 = blockIdx.y * 32;
    const float* xeb = xe + (size_t)b * 64 * NPIX + pix;
    float acc[32];
#pragma unroll
    for (int o = 0; o < 32; ++o) acc[o] = vb[oc0 + o];
    for (int c = 0; c < 64; ++c) {
        float ev = xeb[(size_t)c * NPIX];
#pragma unroll
        for (int o = 0; o < 32; ++o) acc[o] += vw[(oc0 + o) * 64 + c] * ev;
    }
#pragma unroll
    for (int o = 0; o < 32; ++o)
        v[((size_t)b * 64 + oc0 + o) * NPIX + pix] = acc[o];
}

// ---------------------------------------------------------------------------
// Pass 1: column attention partials.  Block = (w, b).  Computes, per pixel
// (h,w): m_col, s_col and unnormalized outH written TRANSPOSED:
// outT[b][w][c][h]  (coalesced for this block).
// ---------------------------------------------------------------------------
__global__ __launch_bounds__(256) void attn_col_kernel(
    const float* __restrict__ q, const float* __restrict__ k,
    const float* __restrict__ v,
    float* __restrict__ outT, float* __restrict__ mC, float* __restrict__ sC)
{
    __shared__ float qs[8][128];
    __shared__ float ks[8][128];
    __shared__ float vs[64][129];
    __shared__ float E[32][129];

    const int tid = threadIdx.x;
    const int w = blockIdx.x;
    const int b = blockIdx.y;

    for (int i = tid; i < 1024; i += 256) {
        int c = i >> 7, h = i & 127;
        qs[c][h] = q[(((size_t)b * 8 + c) * 128 + h) * 128 + w];
        ks[c][h] = k[(((size_t)b * 8 + c) * 128 + h) * 128 + w];
    }
    for (int i = tid; i < 8192; i += 256) {
        int c = i >> 7, j = i & 127;
        vs[c][j] = v[(((size_t)b * 64 + c) * 128 + j) * 128 + w];
    }
    __syncthreads();

    const int jj = tid & 127;
    const int hi = tid >> 7;

    for (int hc = 0; hc < 4; ++hc) {
        const int h0 = hc * 32;
        // logits E[i][j] = sum_c q[c][h0+i] * k[c][j], diag masked
#pragma unroll
        for (int e = 0; e < 16; ++e) {
            int i = e * 2 + hi;
            float a = 0.f;
#pragma unroll
            for (int c = 0; c < 8; ++c) a += qs[c][h0 + i] * ks[c][jj];
            if (h0 + i == jj) a = -1e30f;
            E[i][jj] = a;
        }
        __syncthreads();
        // per-row stats + exp overwrite
        if (tid < 32) {
            int i = tid;
            float m = -1e30f;
            for (int j = 0; j < 128; ++j) m = fmaxf(m, E[i][j]);
            float s = 0.f;
            for (int j = 0; j < 128; ++j) {
                float pp = __expf(E[i][j] - m);
                E[i][j] = pp;
                s += pp;
            }
            mC[((size_t)b * 128 + (h0 + i)) * 128 + w] = m;
            sC[((size_t)b * 128 + (h0 + i)) * 128 + w] = s;
        }
        __syncthreads();
        // out[c][i] = sum_j E[i][j] * vs[c][j]
        {
            int c0 = (tid & 15) * 4;
            int i0 = (tid >> 4) * 2;
            float acc[4][2];
#pragma unroll
            for (int a = 0; a < 4; ++a) { acc[a][0] = 0.f; acc[a][1] = 0.f; }
            for (int j = 0; j < 128; ++j) {
                float p0 = E[i0][j], p1 = E[i0 + 1][j];
#pragma unroll
                for (int a = 0; a < 4; ++a) {
                    float vv = vs[c0 + a][j];
                    acc[a][0] += vv * p0;
                    acc[a][1] += vv * p1;
                }
            }
#pragma unroll
            for (int a = 0; a < 4; ++a) {
                size_t base = (((size_t)b * 128 + w) * 64 + (c0 + a)) * 128 + h0 + i0;
                outT[base]     = acc[a][0];
                outT[base + 1] = acc[a][1];
            }
        }
        __syncthreads();
    }
}

// ---------------------------------------------------------------------------
// Pass 2: row attention partials.  Block = (h, b).  Fully coalesced.
// Writes standard layout outS[b][c][h][w].
// ---------------------------------------------------------------------------
__global__ __launch_bounds__(256) void attn_row_kernel(
    const float* __restrict__ q, const float* __restrict__ k,
    const float* __restrict__ v,
    float* __restrict__ outS, float* __restrict__ mR, float* __restrict__ sR)
{
    __shared__ float qs[8][128];
    __shared__ float ks[8][128];
    __shared__ float vs[64][129];
    __shared__ float E[32][129];

    const int tid = threadIdx.x;
    const int h = blockIdx.x;
    const int b = blockIdx.y;

    for (int i = tid; i < 1024; i += 256) {
        int c = i >> 7, x = i & 127;
        qs[c][x] = q[(((size_t)b * 8 + c) * 128 + h) * 128 + x];
        ks[c][x] = k[(((size_t)b * 8 + c) * 128 + h) * 128 + x];
    }
    for (int i = tid; i < 8192; i += 256) {
        int c = i >> 7, j = i & 127;
        vs[c][j] = v[(((size_t)b * 64 + c) * 128 + h) * 128 + j];
    }
    __syncthreads();

    const int jj = tid & 127;
    const int hi = tid >> 7;

    for (int wc = 0; wc < 4; ++wc) {
        const int w0 = wc * 32;
#pragma unroll
        for (int e = 0; e < 16; ++e) {
            int i = e * 2 + hi;
            float a = 0.f;
#pragma unroll
            for (int c = 0; c < 8; ++c) a += qs[c][w0 + i] * ks[c][jj];
            E[i][jj] = a;              // no diag mask on row part
        }
        __syncthreads();
        if (tid < 32) {
            int i = tid;
            float m = -1e30f;
            for (int j = 0; j < 128; ++j) m = fmaxf(m, E[i][j]);
            float s = 0.f;
            for (int j = 0; j < 128; ++j) {
                float pp = __expf(E[i][j] - m);
                E[i][j] = pp;
                s += pp;
            }
            mR[((size_t)b * 128 + h) * 128 + (w0 + i)] = m;
            sR[((size_t)b * 128 + h) * 128 + (w0 + i)] = s;
        }
        __syncthreads();
        {
            int c0 = (tid & 15) * 4;
            int i0 = (tid >> 4) * 2;
            float acc[4][2];
#pragma unroll
            for (int a = 0; a < 4; ++a) { acc[a][0] = 0.f; acc[a][1] = 0.f; }
            for (int j = 0; j < 128; ++j) {
                float p0 = E[i0][j], p1 = E[i0 + 1][j];
#pragma unroll
                for (int a = 0; a < 4; ++a) {
                    float vv = vs[c0 + a][j];
                    acc[a][0] += vv * p0;
                    acc[a][1] += vv * p1;
                }
            }
#pragma unroll
            for (int a = 0; a < 4; ++a) {
                size_t base = (((size_t)b * 64 + (c0 + a)) * 128 + h) * 128 + w0 + i0;
                outS[base]     = acc[a][0];
                outS[base + 1] = acc[a][1];
            }
        }
        __syncthreads();
    }
}

// ---------------------------------------------------------------------------
// Pass 3: merge col/row partial softmaxes, s = outH+outW+2, residual update
// xe += g1*s, xq += g2*s  (in place).  Block = (h, b).
// ---------------------------------------------------------------------------
__global__ __launch_bounds__(256) void merge_kernel(
    const float* __restrict__ T1, const float* __restrict__ S2,
    const float* __restrict__ mC, const float* __restrict__ sC,
    const float* __restrict__ mR, const float* __restrict__ sR,
    const float* __restrict__ g1p, const float* __restrict__ g2p,
    float* __restrict__ xe, float* __restrict__ xq)
{
    __shared__ float mc[128], sc[128], mr[128], sr[128];
    const int tid = threadIdx.x;
    const int h = blockIdx.x;
    const int b = blockIdx.y;
    if (tid < 128) {
        size_t o = ((size_t)b * 128 + h) * 128 + tid;
        mc[tid] = mC[o]; sc[tid] = sC[o];
        mr[tid] = mR[o]; sr[tid] = sR[o];
    }
    float g1 = g1p[0], g2 = g2p[0];
    __syncthreads();
    for (int i = tid; i < 8192; i += 256) {
        int c = i >> 7, w = i & 127;
        float oc_ = T1[(((size_t)b * 128 + w) * 64 + c) * 128 + h];
        float ow_ = S2[(((size_t)b * 64 + c) * 128 + h) * 128 + w];
        float m  = fmaxf(mc[w], mr[w]);
        float ec = __expf(mc[w] - m);
        float er = __expf(mr[w] - m);
        float denom = sc[w] * ec + sr[w] * er;
        float sval = (oc_ * ec + ow_ * er) / denom + 2.0f;   // +2 from outLR+outRL
        size_t p = (((size_t)b * 64 + c) * 128 + h) * 128 + w;
        xe[p] += g1 * sval;
        xq[p] += g2 * sval;
    }
}

// ---------------------------------------------------------------------------
extern "C" void kernel_launch(void* const* d_in, const int* in_sizes, int n_in,
                              void* d_out, int out_size, void* d_ws, size_t ws_size,
                              hipStream_t stream)
{
    const float* x_ex = (const float*)d_in[0];
    const float* x_q  = (const float*)d_in[1];
    const float* cew  = (const float*)d_in[2];
    const float* bes  = (const float*)d_in[3];
    const float* beb  = (const float*)d_in[4];
    const float* cqw  = (const float*)d_in[5];
    const float* bqs  = (const float*)d_in[6];
    const float* bqb  = (const float*)d_in[7];
    const float* qw   = (const float*)d_in[8];
    const float* qb   = (const float*)d_in[9];
    const float* kw   = (const float*)d_in[10];
    const float* kb   = (const float*)d_in[11];
    const float* vw   = (const float*)d_in[12];
    const float* vb   = (const float*)d_in[13];
    const float* g1   = (const float*)d_in[14];
    const float* g2   = (const float*)d_in[15];
    const float* tew  = (const float*)d_in[16];
    const float* bts  = (const float*)d_in[17];
    const float* btb  = (const float*)d_in[18];
    const float* tqw  = (const float*)d_in[19];
    const float* btqs = (const float*)d_in[20];
    const float* btqb = (const float*)d_in[21];

    float* out = (float*)d_out;

    // workspace layout (floats)
    float* Wf = (float*)d_ws;
    float* xe = Wf;
    float* xq = Wf + C64SZ;
    float* v  = Wf + 2 * C64SZ;
    float* q  = Wf + 3 * C64SZ;
    float* k  = q + QSZ;

    // d_out doubles as scratch for attention partials (overwritten at the end)
    float* T1 = out;                       // [b][w][c][h]  8,388,608
    float* S2 = out + C64SZ;               // [b][c][h][w]  8,388,608
    float* mC = out + 2 * C64SZ;
    float* sC = mC + STATSZ;
    float* mR = sC + STATSZ;
    float* sR = mR + STATSZ;

    // head convs: 256 -> 64
    conv3x3_bn_relu<256><<<dim3(32, 8, 2), 256, 0, stream>>>(x_ex, cew, bes, beb, xe, 64);
    conv3x3_bn_relu<256><<<dim3(32, 8, 2), 256, 0, stream>>>(x_q,  cqw, bqs, bqb, xq, 64);

    for (int round = 0; round < 2; ++round) {
        qk_kernel<<<512, 256, 0, stream>>>(xq, xe, qw, qb, kw, kb, q, k);
        v_kernel<<<dim3(512, 2), 256, 0, stream>>>(xe, vw, vb, v);
        attn_col_kernel<<<dim3(128, 8), 256, 0, stream>>>(q, k, v, T1, mC, sC);
        attn_row_kernel<<<dim3(128, 8), 256, 0, stream>>>(q, k, v, S2, mR, sR);
        merge_kernel<<<dim3(128, 8), 256, 0, stream>>>(T1, S2, mC, sC, mR, sR, g1, g2, xe, xq);
    }

    // tail convs: 64 -> 256, straight into d_out
    conv3x3_bn_relu<64><<<dim3(32, 8, 8), 256, 0, stream>>>(xe, tew, bts, btb, out, 256);
    conv3x3_bn_relu<64><<<dim3(32, 8, 8), 256, 0, stream>>>(xq, tqw, btqs, btqb, out + OUTHALF, 256);
}

// Round 2
// 1566.031 us; speedup vs baseline: 2.6840x; 2.6840x over previous
//
#include <hip/hip_runtime.h>

// Sizes
constexpr int BB = 8;
constexpr int CC = 256;
constexpr int HH = 128;
constexpr int WW = 128;
constexpr int INTER = 64;
constexpr size_t NPIX = (size_t)HH * WW;            // 16384
constexpr size_t C64SZ = (size_t)BB * INTER * NPIX; // 8,388,608
constexpr size_t QSZ   = (size_t)BB * 8 * NPIX;     // 1,048,576
constexpr size_t STATSZ = (size_t)BB * HH * WW;     // 131,072
constexpr size_t OUTHALF = (size_t)BB * CC * NPIX;  // 33,554,432
constexpr size_t WT_ELEMS = (size_t)9 * 64 * 256;   // 147456 (same for head & tail)

typedef __attribute__((ext_vector_type(8))) __bf16 bf16x8;
typedef __attribute__((ext_vector_type(4))) float f32x4;
typedef __attribute__((ext_vector_type(4))) short short4v;

__device__ inline short f2bf(float f) {
    union { float f; unsigned u; } a; a.f = f;
    unsigned r = a.u + 0x7fffu + ((a.u >> 16) & 1u);   // RNE
    return (short)(r >> 16);
}

// ---------------------------------------------------------------------------
// Weight transform: wgt fp32 [OC][IC][3][3] -> wt bf16 [pos=dh*3+dw][OC][IC]
// ---------------------------------------------------------------------------
__global__ __launch_bounds__(256) void wprep_kernel(
    const float* __restrict__ wgt, short* __restrict__ wt, int OC, int IC)
{
    int idx = blockIdx.x * 256 + threadIdx.x;
    int n = 9 * OC * IC;
    if (idx >= n) return;
    int ic = idx & (IC - 1);
    int t  = idx / IC;
    int oc = t & (OC - 1);
    int pos = t / OC;
    wt[idx] = f2bf(wgt[((size_t)oc * IC + ic) * 9 + pos]);
}

// ---------------------------------------------------------------------------
// Conv 3x3 (pad 1) + BN + ReLU via bf16 MFMA implicit GEMM.
// Block: R output rows x 128 cols, all OC.  4 waves of 64.
// LDS: xs[row][wpos 0..129][ic 0..31 (pad to 40)] bf16, per 32-ic chunk.
// A (weights) streamed from global (pre-transformed, [pos][oc][ic], L2-hot).
// grid = (8 batches [XCD-affine], H/R strips)
// ---------------------------------------------------------------------------
template<int IC, int OC, int R, int NT>
__global__ __launch_bounds__(256, 2) void conv_mfma(
    const float* __restrict__ x, const short* __restrict__ wt,
    const float* __restrict__ bns, const float* __restrict__ bnb,
    float* __restrict__ out)
{
    constexpr int ROWS = R + 2;
    constexpr int NCH  = IC / 32;
    constexpr int NPIXT = R * 128;
    constexpr int NWN  = NPIXT / (NT * 16);   // waves along N

    __shared__ __align__(16) short xs[ROWS * 130 * 40];

    const int tid = threadIdx.x;
    const int b   = blockIdx.x;
    const int h0  = blockIdx.y * R;
    const int l   = tid & 63;
    const int ln  = l & 15;
    const int q   = l >> 4;
    const int wv  = tid >> 6;
    const int nbase = (wv % NWN) * (NT * 16);
    const int oc0w  = (wv / NWN) * 64;

    f32x4 acc[4][NT];
#pragma unroll
    for (int mt = 0; mt < 4; ++mt)
#pragma unroll
        for (int nt = 0; nt < NT; ++nt)
            acc[mt][nt] = (f32x4){0.f, 0.f, 0.f, 0.f};

    const float* xb = x + (size_t)b * IC * NPIX;

    for (int ch = 0; ch < NCH; ++ch) {
        const int ic0 = ch * 32;
        // ---- stage 32 ic x ROWS rows x 130 cols (transposed, bf16) ----
        constexpr int UNITS = ROWS * 8;           // (row, 4-ic group)
        for (int u = 0; u < UNITS; u += 2) {
            int unit = u + (tid >> 7);
            int col  = tid & 127;
            int row  = unit >> 3;
            int icg  = unit & 7;
            int ic   = ic0 + icg * 4;
            int grow = h0 - 1 + row;
            short4v pk;
            if ((unsigned)grow < 128u) {
                const float* p = xb + ((size_t)ic * 128 + grow) * 128 + col;
                pk.x = f2bf(p[0]);
                pk.y = f2bf(p[16384]);
                pk.z = f2bf(p[32768]);
                pk.w = f2bf(p[49152]);
            } else {
                pk.x = 0; pk.y = 0; pk.z = 0; pk.w = 0;
            }
            *(short4v*)&xs[(row * 130 + col + 1) * 40 + icg * 4] = pk;
        }
        // halo columns (gcol -1 and 128 are outside image -> zero)
        if (tid < ROWS * 16) {
            int row  = tid >> 4;
            int colh = (tid & 8) ? 129 : 0;
            int icg  = tid & 7;
            short4v z; z.x = 0; z.y = 0; z.z = 0; z.w = 0;
            *(short4v*)&xs[(row * 130 + colh) * 40 + icg * 4] = z;
        }
        __syncthreads();

        // ---- 9 accumulating GEMM positions over this 32-ic chunk ----
        for (int dh = 0; dh < 3; ++dh) {
#pragma unroll
            for (int dw = 0; dw < 3; ++dw) {
                const int pos = dh * 3 + dw;
                bf16x8 a[4];
#pragma unroll
                for (int mt = 0; mt < 4; ++mt)
                    a[mt] = *(const bf16x8*)(wt +
                        (size_t)(pos * OC + oc0w + mt * 16 + ln) * IC + ic0 + q * 8);
#pragma unroll
                for (int nt = 0; nt < NT; ++nt) {
                    int pix  = nbase + nt * 16 + ln;
                    int rowi = (pix >> 7) + dh;
                    int wpos = (pix & 127) + dw;
                    bf16x8 bfr = *(const bf16x8*)&xs[(rowi * 130 + wpos) * 40 + q * 8];
#pragma unroll
                    for (int mt = 0; mt < 4; ++mt)
                        acc[mt][nt] = __builtin_amdgcn_mfma_f32_16x16x32_bf16(
                            a[mt], bfr, acc[mt][nt], 0, 0, 0);
                }
            }
        }
        __syncthreads();
    }

    // ---- epilogue: BN + ReLU, store fp32 NCHW ----
#pragma unroll
    for (int mt = 0; mt < 4; ++mt) {
#pragma unroll
        for (int r = 0; r < 4; ++r) {
            int oc = oc0w + mt * 16 + q * 4 + r;
            float s   = bns[oc];
            float bb2 = bnb[oc];
#pragma unroll
            for (int nt = 0; nt < NT; ++nt) {
                int pix = nbase + nt * 16 + ln;
                int h = h0 + (pix >> 7), w = pix & 127;
                float v = fmaxf(acc[mt][nt][r] * s + bb2, 0.f);
                out[(((size_t)b * OC + oc) * 128 + h) * 128 + w] = v;
            }
        }
    }
}

// ---------------------------------------------------------------------------
// QK projection: q = q_w @ xq + q_b (8 ch), k = k_w @ xe + k_b (8 ch)
// ---------------------------------------------------------------------------
__global__ __launch_bounds__(256) void qk_kernel(
    const float* __restrict__ xq, const float* __restrict__ xe,
    const float* __restrict__ qw, const float* __restrict__ qb,
    const float* __restrict__ kw, const float* __restrict__ kb,
    float* __restrict__ q, float* __restrict__ k)
{
    size_t p = (size_t)blockIdx.x * 256 + threadIdx.x;
    int b = (int)(p >> 14);
    int pix = (int)(p & 16383);
    const float* xqb = xq + (size_t)b * 64 * NPIX + pix;
    const float* xeb = xe + (size_t)b * 64 * NPIX + pix;
    float qa[8], ka[8];
#pragma unroll
    for (int o = 0; o < 8; ++o) { qa[o] = qb[o]; ka[o] = kb[o]; }
    for (int c = 0; c < 64; ++c) {
        float xv = xqb[(size_t)c * NPIX];
        float ev = xeb[(size_t)c * NPIX];
#pragma unroll
        for (int o = 0; o < 8; ++o) {
            qa[o] += qw[o * 64 + c] * xv;
            ka[o] += kw[o * 64 + c] * ev;
        }
    }
#pragma unroll
    for (int o = 0; o < 8; ++o) {
        q[((size_t)b * 8 + o) * NPIX + pix] = qa[o];
        k[((size_t)b * 8 + o) * NPIX + pix] = ka[o];
    }
}

// ---------------------------------------------------------------------------
// V projection: v = v_w @ xe + v_b (64 ch), 32 oc per z-slice
// ---------------------------------------------------------------------------
__global__ __launch_bounds__(256) void v_kernel(
    const float* __restrict__ xe,
    const float* __restrict__ vw, const float* __restrict__ vb,
    float* __restrict__ v)
{
    size_t p = (size_t)blockIdx.x * 256 + threadIdx.x;
    int b = (int)(p >> 14);
    int pix = (int)(p & 16383);
    int oc0 = blockIdx.y * 32;
    const float* xeb = xe + (size_t)b * 64 * NPIX + pix;
    float acc[32];
#pragma unroll
    for (int o = 0; o < 32; ++o) acc[o] = vb[oc0 + o];
    for (int c = 0; c < 64; ++c) {
        float ev = xeb[(size_t)c * NPIX];
#pragma unroll
        for (int o = 0; o < 32; ++o) acc[o] += vw[(oc0 + o) * 64 + c] * ev;
    }
#pragma unroll
    for (int o = 0; o < 32; ++o)
        v[((size_t)b * 64 + oc0 + o) * NPIX + pix] = acc[o];
}

// ---------------------------------------------------------------------------
// Pass 1: column attention partials.
// ---------------------------------------------------------------------------
__global__ __launch_bounds__(256) void attn_col_kernel(
    const float* __restrict__ q, const float* __restrict__ k,
    const float* __restrict__ v,
    float* __restrict__ outT, float* __restrict__ mC, float* __restrict__ sC)
{
    __shared__ float qs[8][128];
    __shared__ float ks[8][128];
    __shared__ float vs[64][129];
    __shared__ float E[32][129];

    const int tid = threadIdx.x;
    const int w = blockIdx.x;
    const int b = blockIdx.y;

    for (int i = tid; i < 1024; i += 256) {
        int c = i >> 7, h = i & 127;
        qs[c][h] = q[(((size_t)b * 8 + c) * 128 + h) * 128 + w];
        ks[c][h] = k[(((size_t)b * 8 + c) * 128 + h) * 128 + w];
    }
    for (int i = tid; i < 8192; i += 256) {
        int c = i >> 7, j = i & 127;
        vs[c][j] = v[(((size_t)b * 64 + c) * 128 + j) * 128 + w];
    }
    __syncthreads();

    const int jj = tid & 127;
    const int hi = tid >> 7;

    for (int hc = 0; hc < 4; ++hc) {
        const int h0 = hc * 32;
#pragma unroll
        for (int e = 0; e < 16; ++e) {
            int i = e * 2 + hi;
            float a = 0.f;
#pragma unroll
            for (int c = 0; c < 8; ++c) a += qs[c][h0 + i] * ks[c][jj];
            if (h0 + i == jj) a = -1e30f;
            E[i][jj] = a;
        }
        __syncthreads();
        if (tid < 32) {
            int i = tid;
            float m = -1e30f;
            for (int j = 0; j < 128; ++j) m = fmaxf(m, E[i][j]);
            float s = 0.f;
            for (int j = 0; j < 128; ++j) {
                float pp = __expf(E[i][j] - m);
                E[i][j] = pp;
                s += pp;
            }
            mC[((size_t)b * 128 + (h0 + i)) * 128 + w] = m;
            sC[((size_t)b * 128 + (h0 + i)) * 128 + w] = s;
        }
        __syncthreads();
        {
            int c0 = (tid & 15) * 4;
            int i0 = (tid >> 4) * 2;
            float acc[4][2];
#pragma unroll
            for (int a = 0; a < 4; ++a) { acc[a][0] = 0.f; acc[a][1] = 0.f; }
            for (int j = 0; j < 128; ++j) {
                float p0 = E[i0][j], p1 = E[i0 + 1][j];
#pragma unroll
                for (int a = 0; a < 4; ++a) {
                    float vv = vs[c0 + a][j];
                    acc[a][0] += vv * p0;
                    acc[a][1] += vv * p1;
                }
            }
#pragma unroll
            for (int a = 0; a < 4; ++a) {
                size_t base = (((size_t)b * 128 + w) * 64 + (c0 + a)) * 128 + h0 + i0;
                outT[base]     = acc[a][0];
                outT[base + 1] = acc[a][1];
            }
        }
        __syncthreads();
    }
}

// ---------------------------------------------------------------------------
// Pass 2: row attention partials.
// ---------------------------------------------------------------------------
__global__ __launch_bounds__(256) void attn_row_kernel(
    const float* __restrict__ q, const float* __restrict__ k,
    const float* __restrict__ v,
    float* __restrict__ outS, float* __restrict__ mR, float* __restrict__ sR)
{
    __shared__ float qs[8][128];
    __shared__ float ks[8][128];
    __shared__ float vs[64][129];
    __shared__ float E[32][129];

    const int tid = threadIdx.x;
    const int h = blockIdx.x;
    const int b = blockIdx.y;

    for (int i = tid; i < 1024; i += 256) {
        int c = i >> 7, x = i & 127;
        qs[c][x] = q[(((size_t)b * 8 + c) * 128 + h) * 128 + x];
        ks[c][x] = k[(((size_t)b * 8 + c) * 128 + h) * 128 + x];
    }
    for (int i = tid; i < 8192; i += 256) {
        int c = i >> 7, j = i & 127;
        vs[c][j] = v[(((size_t)b * 64 + c) * 128 + h) * 128 + j];
    }
    __syncthreads();

    const int jj = tid & 127;
    const int hi = tid >> 7;

    for (int wc = 0; wc < 4; ++wc) {
        const int w0 = wc * 32;
#pragma unroll
        for (int e = 0; e < 16; ++e) {
            int i = e * 2 + hi;
            float a = 0.f;
#pragma unroll
            for (int c = 0; c < 8; ++c) a += qs[c][w0 + i] * ks[c][jj];
            E[i][jj] = a;
        }
        __syncthreads();
        if (tid < 32) {
            int i = tid;
            float m = -1e30f;
            for (int j = 0; j < 128; ++j) m = fmaxf(m, E[i][j]);
            float s = 0.f;
            for (int j = 0; j < 128; ++j) {
                float pp = __expf(E[i][j] - m);
                E[i][j] = pp;
                s += pp;
            }
            mR[((size_t)b * 128 + h) * 128 + (w0 + i)] = m;
            sR[((size_t)b * 128 + h) * 128 + (w0 + i)] = s;
        }
        __syncthreads();
        {
            int c0 = (tid & 15) * 4;
            int i0 = (tid >> 4) * 2;
            float acc[4][2];
#pragma unroll
            for (int a = 0; a < 4; ++a) { acc[a][0] = 0.f; acc[a][1] = 0.f; }
            for (int j = 0; j < 128; ++j) {
                float p0 = E[i0][j], p1 = E[i0 + 1][j];
#pragma unroll
                for (int a = 0; a < 4; ++a) {
                    float vv = vs[c0 + a][j];
                    acc[a][0] += vv * p0;
                    acc[a][1] += vv * p1;
                }
            }
#pragma unroll
            for (int a = 0; a < 4; ++a) {
                size_t base = (((size_t)b * 64 + (c0 + a)) * 128 + h) * 128 + w0 + i0;
                outS[base]     = acc[a][0];
                outS[base + 1] = acc[a][1];
            }
        }
        __syncthreads();
    }
}

// ---------------------------------------------------------------------------
// Pass 3: merge partial softmaxes, s = outH+outW+2, residual update in place.
// ---------------------------------------------------------------------------
__global__ __launch_bounds__(256) void merge_kernel(
    const float* __restrict__ T1, const float* __restrict__ S2,
    const float* __restrict__ mC, const float* __restrict__ sC,
    const float* __restrict__ mR, const float* __restrict__ sR,
    const float* __restrict__ g1p, const float* __restrict__ g2p,
    float* __restrict__ xe, float* __restrict__ xq)
{
    __shared__ float mc[128], sc[128], mr[128], sr[128];
    const int tid = threadIdx.x;
    const int h = blockIdx.x;
    const int b = blockIdx.y;
    if (tid < 128) {
        size_t o = ((size_t)b * 128 + h) * 128 + tid;
        mc[tid] = mC[o]; sc[tid] = sC[o];
        mr[tid] = mR[o]; sr[tid] = sR[o];
    }
    float g1 = g1p[0], g2 = g2p[0];
    __syncthreads();
    for (int i = tid; i < 8192; i += 256) {
        int c = i >> 7, w = i & 127;
        float oc_ = T1[(((size_t)b * 128 + w) * 64 + c) * 128 + h];
        float ow_ = S2[(((size_t)b * 64 + c) * 128 + h) * 128 + w];
        float m  = fmaxf(mc[w], mr[w]);
        float ec = __expf(mc[w] - m);
        float er = __expf(mr[w] - m);
        float denom = sc[w] * ec + sr[w] * er;
        float sval = (oc_ * ec + ow_ * er) / denom + 2.0f;
        size_t p = (((size_t)b * 64 + c) * 128 + h) * 128 + w;
        xe[p] += g1 * sval;
        xq[p] += g2 * sval;
    }
}

// ---------------------------------------------------------------------------
extern "C" void kernel_launch(void* const* d_in, const int* in_sizes, int n_in,
                              void* d_out, int out_size, void* d_ws, size_t ws_size,
                              hipStream_t stream)
{
    const float* x_ex = (const float*)d_in[0];
    const float* x_q  = (const float*)d_in[1];
    const float* cew  = (const float*)d_in[2];
    const float* bes  = (const float*)d_in[3];
    const float* beb  = (const float*)d_in[4];
    const float* cqw  = (const float*)d_in[5];
    const float* bqs  = (const float*)d_in[6];
    const float* bqb  = (const float*)d_in[7];
    const float* qw   = (const float*)d_in[8];
    const float* qb   = (const float*)d_in[9];
    const float* kw   = (const float*)d_in[10];
    const float* kb   = (const float*)d_in[11];
    const float* vw   = (const float*)d_in[12];
    const float* vb   = (const float*)d_in[13];
    const float* g1   = (const float*)d_in[14];
    const float* g2   = (const float*)d_in[15];
    const float* tew  = (const float*)d_in[16];
    const float* bts  = (const float*)d_in[17];
    const float* btb  = (const float*)d_in[18];
    const float* tqw  = (const float*)d_in[19];
    const float* btqs = (const float*)d_in[20];
    const float* btqb = (const float*)d_in[21];

    float* out = (float*)d_out;

    // workspace: [4 bf16 weight arrays | fp32 xe xq v q k]
    short* wt0 = (short*)d_ws;                 // head ex
    short* wt1 = wt0 + WT_ELEMS;               // head q
    short* wt2 = wt1 + WT_ELEMS;               // tail ex
    short* wt3 = wt2 + WT_ELEMS;               // tail q
    float* Wf  = (float*)(wt3 + WT_ELEMS);
    float* xe = Wf;
    float* xq = Wf + C64SZ;
    float* v  = Wf + 2 * C64SZ;
    float* q  = Wf + 3 * C64SZ;
    float* k  = q + QSZ;

    // d_out doubles as scratch for attention partials
    float* T1 = out;
    float* S2 = out + C64SZ;
    float* mC = out + 2 * C64SZ;
    float* sC = mC + STATSZ;
    float* mR = sC + STATSZ;
    float* sR = mR + STATSZ;

    // weight transforms (tiny)
    wprep_kernel<<<576, 256, 0, stream>>>(cew, wt0, 64, 256);
    wprep_kernel<<<576, 256, 0, stream>>>(cqw, wt1, 64, 256);
    wprep_kernel<<<576, 256, 0, stream>>>(tew, wt2, 256, 64);
    wprep_kernel<<<576, 256, 0, stream>>>(tqw, wt3, 256, 64);

    // head convs: 256 -> 64 (R=2 rows/block, NT=4)
    conv_mfma<256, 64, 2, 4><<<dim3(8, 64), 256, 0, stream>>>(x_ex, wt0, bes, beb, xe);
    conv_mfma<256, 64, 2, 4><<<dim3(8, 64), 256, 0, stream>>>(x_q,  wt1, bqs, bqb, xq);

    for (int round = 0; round < 2; ++round) {
        qk_kernel<<<512, 256, 0, stream>>>(xq, xe, qw, qb, kw, kb, q, k);
        v_kernel<<<dim3(512, 2), 256, 0, stream>>>(xe, vw, vb, v);
        attn_col_kernel<<<dim3(128, 8), 256, 0, stream>>>(q, k, v, T1, mC, sC);
        attn_row_kernel<<<dim3(128, 8), 256, 0, stream>>>(q, k, v, S2, mR, sR);
        merge_kernel<<<dim3(128, 8), 256, 0, stream>>>(T1, S2, mC, sC, mR, sR, g1, g2, xe, xq);
    }

    // tail convs: 64 -> 256 (R=1 row/block, NT=8)
    conv_mfma<64, 256, 1, 8><<<dim3(8, 128), 256, 0, stream>>>(xe, wt2, bts, btb, out);
    conv_mfma<64, 256, 1, 8><<<dim3(8, 128), 256, 0, stream>>>(xq, wt3, btqs, btqb, out + OUTHALF);
}